// Round 1
// baseline (2738.606 us; speedup 1.0000x reference)
//
#include <hip/hip_runtime.h>
#include <math.h>

// Problem constants (fixed by harness): N=768, T=8, H=128, F=128, NZ=64, G=64, D=320, n_next=12
// ws layout (float offsets)
#define ZX_OFF  0            // [8][768][512] = 3145728
#define H_OFF   3145728      // [768][128]
#define C_OFF   3244032      // [768][128]
#define G_OFF   3342336      // [768][64]
#define S0_OFF  3391488      // [768]
#define WTD_OFF 3392256      // [768][128]

#define DOT4(a_, w_, v_) a_ += w_.x*v_.x + w_.y*v_.y + w_.z*v_.z + w_.w*v_.w

__device__ __forceinline__ float sigm(float x) { return 1.0f / (1.0f + __expf(-x)); }
__device__ __forceinline__ float lrelu(float u) { return u >= 0.f ? u : 0.2f * u; }

// ---------------- Zx = (emb(obsv)) @ W_ih^T + b_ih + b_hh, for all 8 steps ----------------
// grid 384 (6144 rows / 16), block 256. row = t*768 + n.
__global__ __launch_bounds__(256) void k_zx(
    const float* __restrict__ obsv, const float* __restrict__ Wemb,
    const float* __restrict__ bemb, const float* __restrict__ Wih,
    const float* __restrict__ bih, const float* __restrict__ bhh,
    float* __restrict__ ws)
{
  __shared__ float X[16][128];
  const int tid = threadIdx.x;
  const int row0 = blockIdx.x * 16;
  const int t = row0 / 768;
  const int nbase = row0 % 768;

  for (int e = tid; e < 16 * 128; e += 256) {
    int i = e >> 7, j = e & 127;
    float4 ob = *(const float4*)&obsv[((size_t)(nbase + i) * 8 + t) * 4];
    float4 w = *(const float4*)&Wemb[j * 4];
    X[i][j] = bemb[j] + ob.x * w.x + ob.y * w.y + ob.z * w.z + ob.w * w.w;
  }
  __syncthreads();

  for (int task = tid; task < 16 * 128; task += 256) {
    int r4 = task & 127, i = task >> 7;
    int r = r4 * 4;
    float4 acc;
    acc.x = bih[r + 0] + bhh[r + 0];
    acc.y = bih[r + 1] + bhh[r + 1];
    acc.z = bih[r + 2] + bhh[r + 2];
    acc.w = bih[r + 3] + bhh[r + 3];
    for (int k4 = 0; k4 < 32; ++k4) {
      float4 xv = *(const float4*)&X[i][k4 * 4];
      float4 w0 = *(const float4*)&Wih[(size_t)(r + 0) * 128 + k4 * 4];
      float4 w1 = *(const float4*)&Wih[(size_t)(r + 1) * 128 + k4 * 4];
      float4 w2 = *(const float4*)&Wih[(size_t)(r + 2) * 128 + k4 * 4];
      float4 w3 = *(const float4*)&Wih[(size_t)(r + 3) * 128 + k4 * 4];
      DOT4(acc.x, w0, xv);
      DOT4(acc.y, w1, xv);
      DOT4(acc.z, w2, xv);
      DOT4(acc.w, w3, xv);
    }
    *(float4*)&ws[ZX_OFF + (size_t)(row0 + i) * 512 + r] = acc;
  }
}

// ---------------- encoder LSTM: 8 recurrent steps, 4 agents/block ----------------
// grid 192, block 128. Thread t owns h-dim t (gate quad rows t, t+128, t+256, t+384).
__global__ __launch_bounds__(128) void k_enc(
    const float* __restrict__ Whh, float* __restrict__ ws)
{
  __shared__ float hs[4][128];
  const int t = threadIdx.x;
  const int n0 = blockIdx.x * 4;
  float c[4] = {0.f, 0.f, 0.f, 0.f};

  for (int step = 0; step < 8; ++step) {
    float acc[4][4];
#pragma unroll
    for (int q = 0; q < 4; ++q)
#pragma unroll
      for (int a = 0; a < 4; ++a)
        acc[q][a] = ws[ZX_OFF + ((size_t)step * 768 + n0 + a) * 512 + q * 128 + t];
    if (step > 0) {
      for (int k4 = 0; k4 < 32; ++k4) {
        float4 hv0 = *(const float4*)&hs[0][k4 * 4];
        float4 hv1 = *(const float4*)&hs[1][k4 * 4];
        float4 hv2 = *(const float4*)&hs[2][k4 * 4];
        float4 hv3 = *(const float4*)&hs[3][k4 * 4];
#pragma unroll
        for (int q = 0; q < 4; ++q) {
          float4 w = *(const float4*)&Whh[(size_t)(q * 128 + t) * 128 + k4 * 4];
          DOT4(acc[q][0], w, hv0);
          DOT4(acc[q][1], w, hv1);
          DOT4(acc[q][2], w, hv2);
          DOT4(acc[q][3], w, hv3);
        }
      }
    }
    __syncthreads();
#pragma unroll
    for (int a = 0; a < 4; ++a) {
      float ci = sigm(acc[1][a]) * c[a] + sigm(acc[0][a]) * tanhf(acc[2][a]);
      c[a] = ci;
      hs[a][t] = sigm(acc[3][a]) * tanhf(ci);
    }
    __syncthreads();
  }
#pragma unroll
  for (int a = 0; a < 4; ++a) {
    ws[H_OFF + (size_t)(n0 + a) * 128 + t] = hs[a][t];
    ws[C_OFF + (size_t)(n0 + a) * 128 + t] = c[a];
  }
}

// ---------------- social fold: Wh = h@Wa^T + ba ; g = Wf3^T Wh ; s0 = bf3 . Wh ----------------
// grid 768 (one per agent), block 128.
__global__ __launch_bounds__(128) void k_social(
    const float* __restrict__ Wa, const float* __restrict__ ba,
    const float* __restrict__ Wf3, const float* __restrict__ bf3,
    float* __restrict__ ws)
{
  __shared__ float hsh[128];
  __shared__ float Wh[128];
  const int n = blockIdx.x, t = threadIdx.x;
  hsh[t] = ws[H_OFF + (size_t)n * 128 + t];
  __syncthreads();
  float acc = ba[t];
  for (int k4 = 0; k4 < 32; ++k4) {
    float4 w = *(const float4*)&Wa[(size_t)t * 128 + k4 * 4];
    float4 h4 = *(const float4*)&hsh[k4 * 4];
    DOT4(acc, w, h4);
  }
  Wh[t] = acc;
  __syncthreads();
  if (t < 64) {
    float g = 0.f;
    for (int f = 0; f < 128; ++f) g += Wf3[(size_t)f * 64 + t] * Wh[f];
    ws[G_OFF + (size_t)n * 64 + t] = g;
  } else {
    int l = t - 64;
    float p = bf3[l] * Wh[l] + bf3[l + 64] * Wh[l + 64];
    for (int off = 32; off > 0; off >>= 1) p += __shfl_xor(p, off);
    if (l == 0) ws[S0_OFF + n] = p;
  }
}

// ---------------- fused pair-features + MLP(3->32->64) + sigma + softmax + S ----------------
// grid 768 (one per agent i), block 64 (lane = j within group).
__global__ __launch_bounds__(64) void k_attn(
    const float* __restrict__ obsv, const float* __restrict__ Wf1,
    const float* __restrict__ bf1, const float* __restrict__ Wf2,
    const float* __restrict__ bf2, float* __restrict__ ws)
{
  __shared__ float w1[96];
  __shared__ float b1[32];
  __shared__ float w2[2048];
  __shared__ float b2[64];
  __shared__ float attn_s[64];
  __shared__ float xi[4];

  const int i = blockIdx.x;
  const int b = i >> 6;
  const int lane = threadIdx.x;
  const int jn = (b << 6) + lane;

  for (int e = lane; e < 96; e += 64) w1[e] = Wf1[e];
  if (lane < 32) b1[lane] = bf1[lane];
  for (int e = lane; e < 2048; e += 64) w2[e] = Wf2[e];
  b2[lane] = bf2[lane];
  if (lane < 4) xi[lane] = obsv[((size_t)i * 8 + 7) * 4 + lane];
  __syncthreads();

  float4 xj = *(const float4*)&obsv[((size_t)jn * 8 + 7) * 4];
  float dpx = xi[0] - xj.x, dpy = xi[1] - xj.y;
  float vix = xi[2], viy = xi[3];
  float dvx = vix - xj.z, dvy = viy - xj.w;
  float l2 = sqrtf(dpx * dpx + dpy * dpy);
  float vnorm = sqrtf(vix * vix + viy * viy);
  float cosv = (dpx * vix + dpy * viy) / (l2 * vnorm + 1e-6f);
  float dv2 = dvx * dvx + dvy * dvy;
  float ttca = -(dpx * dvx + dpy * dvy) / (dv2 + 1e-6f);
  float cax = dpx + ttca * dvx, cay = dpy + ttca * dvy;
  float dca = sqrtf(cax * cax + cay * cay);

  float e1[32];
#pragma unroll
  for (int r = 0; r < 32; ++r)
    e1[r] = fmaxf(w1[r * 3 + 0] * l2 + w1[r * 3 + 1] * cosv + w1[r * 3 + 2] * dca + b1[r], 0.f);

  const float* gp = &ws[G_OFF + (size_t)jn * 64];
  float sig = ws[S0_OFF + jn];
  for (int r = 0; r < 64; ++r) {
    float a2 = b2[r];
#pragma unroll
    for (int k4 = 0; k4 < 8; ++k4) {
      float4 w = *(const float4*)&w2[r * 32 + k4 * 4];
      a2 += w.x * e1[k4 * 4 + 0] + w.y * e1[k4 * 4 + 1] + w.z * e1[k4 * 4 + 2] + w.w * e1[k4 * 4 + 3];
    }
    a2 = fmaxf(a2, 0.f);
    sig += a2 * gp[r];
  }
  if (lane == (i & 63)) sig = -1000.f;

  float m = sig;
  for (int off = 32; off > 0; off >>= 1) m = fmaxf(m, __shfl_xor(m, off));
  float ex = __expf(sig - m);
  float ssum = ex;
  for (int off = 32; off > 0; off >>= 1) ssum += __shfl_xor(ssum, off);
  attn_s[lane] = ex / ssum;
  __syncthreads();

  const float* hbase = &ws[H_OFF + (size_t)(b << 6) * 128];
  float s0a = 0.f, s1a = 0.f;
  for (int j = 0; j < 64; ++j) {
    float aj = attn_s[j];
    s0a += aj * hbase[(size_t)j * 128 + lane];
    s1a += aj * hbase[(size_t)j * 128 + 64 + lane];
  }
  ws[WTD_OFF + (size_t)i * 128 + lane] = s0a;
  ws[WTD_OFF + (size_t)i * 128 + 64 + lane] = s1a;
}

// ---------------- decoder: 12 steps fully fused, 6 agents per block ----------------
// grid 128, block 512.
__global__ __launch_bounds__(512) void k_dec(
    const float* __restrict__ obsv, const float* __restrict__ noise,
    const float* __restrict__ Wemb, const float* __restrict__ bemb,
    const float* __restrict__ Wih, const float* __restrict__ Whh,
    const float* __restrict__ bih, const float* __restrict__ bhh,
    const float* __restrict__ Wd1, const float* __restrict__ bd1,
    const float* __restrict__ Wd2, const float* __restrict__ bd2,
    const float* __restrict__ Wd3, const float* __restrict__ bd3,
    const float* __restrict__ Wd4, const float* __restrict__ bd4,
    float* __restrict__ ws, float* __restrict__ out)
{
  __shared__ float hS[6][128], cS[6][128], wS[6][128];
  __shared__ float nzS[6][64];
  __shared__ float lastS[6][4];
  __shared__ float inpS[6][320], u1S[6][320], u2S[6][160], u3S[6][80];
  __shared__ float xeS[6][128];
  __shared__ float zS[6][512];
  __shared__ float WembS[512], bembS[128], bzS[512];
  __shared__ float bd1S[320], bd2S[160], bd3S[80], bd4S[2];

  const int tid = threadIdx.x;
  const int n0 = blockIdx.x * 6;

  for (int e = tid; e < 6 * 128; e += 512) {
    int a = e >> 7, j = e & 127;
    hS[a][j] = ws[H_OFF + (size_t)(n0 + a) * 128 + j];
    cS[a][j] = ws[C_OFF + (size_t)(n0 + a) * 128 + j];
    wS[a][j] = ws[WTD_OFF + (size_t)(n0 + a) * 128 + j];
  }
  for (int e = tid; e < 6 * 64; e += 512) {
    int a = e >> 6, k = e & 63;
    nzS[a][k] = noise[(size_t)(n0 + a) * 64 + k];
  }
  if (tid < 24) lastS[tid >> 2][tid & 3] = obsv[((size_t)(n0 + (tid >> 2)) * 8 + 7) * 4 + (tid & 3)];
  WembS[tid] = Wemb[tid];
  bzS[tid] = bih[tid] + bhh[tid];
  if (tid < 320) bd1S[tid] = bd1[tid];
  if (tid < 160) bd2S[tid] = bd2[tid];
  if (tid < 128) bembS[tid] = bemb[tid];
  if (tid < 80) bd3S[tid] = bd3[tid];
  if (tid < 2) bd4S[tid] = bd4[tid];
  __syncthreads();

  for (int s = 0; s < 12; ++s) {
    // inp = [h | weighted | noise]
    for (int e = tid; e < 6 * 320; e += 512) {
      int a = e / 320, k = e % 320;
      inpS[a][k] = (k < 128) ? hS[a][k] : (k < 256 ? wS[a][k - 128] : nzS[a][k - 256]);
    }
    __syncthreads();
    // u1 = lrelu(inp @ Wd1^T + bd1)   (320x320)
    for (int task = tid; task < 480; task += 512) {
      int r = (task % 80) * 4, a = task / 80;
      float4 acc = make_float4(bd1S[r], bd1S[r + 1], bd1S[r + 2], bd1S[r + 3]);
      for (int k4 = 0; k4 < 80; ++k4) {
        float4 xv = *(const float4*)&inpS[a][k4 * 4];
        float4 w0 = *(const float4*)&Wd1[(size_t)(r + 0) * 320 + k4 * 4];
        float4 w1 = *(const float4*)&Wd1[(size_t)(r + 1) * 320 + k4 * 4];
        float4 w2 = *(const float4*)&Wd1[(size_t)(r + 2) * 320 + k4 * 4];
        float4 w3 = *(const float4*)&Wd1[(size_t)(r + 3) * 320 + k4 * 4];
        DOT4(acc.x, w0, xv);
        DOT4(acc.y, w1, xv);
        DOT4(acc.z, w2, xv);
        DOT4(acc.w, w3, xv);
      }
      u1S[a][r + 0] = lrelu(acc.x);
      u1S[a][r + 1] = lrelu(acc.y);
      u1S[a][r + 2] = lrelu(acc.z);
      u1S[a][r + 3] = lrelu(acc.w);
    }
    __syncthreads();
    // u2 = lrelu(u1 @ Wd2^T + bd2)   (160x320)
    for (int task = tid; task < 480; task += 512) {
      int r = (task % 80) * 2, a = task / 80;
      float a0 = bd2S[r], a1 = bd2S[r + 1];
      for (int k4 = 0; k4 < 80; ++k4) {
        float4 xv = *(const float4*)&u1S[a][k4 * 4];
        float4 w0 = *(const float4*)&Wd2[(size_t)(r + 0) * 320 + k4 * 4];
        float4 w1 = *(const float4*)&Wd2[(size_t)(r + 1) * 320 + k4 * 4];
        DOT4(a0, w0, xv);
        DOT4(a1, w1, xv);
      }
      u2S[a][r] = lrelu(a0);
      u2S[a][r + 1] = lrelu(a1);
    }
    __syncthreads();
    // u3 = u2 @ Wd3^T + bd3   (80x160, no act)
    for (int task = tid; task < 480; task += 512) {
      int r = task % 80, a = task / 80;
      float acc = bd3S[r];
      for (int k4 = 0; k4 < 40; ++k4) {
        float4 xv = *(const float4*)&u2S[a][k4 * 4];
        float4 w = *(const float4*)&Wd3[(size_t)r * 160 + k4 * 4];
        DOT4(acc, w, xv);
      }
      u3S[a][r] = acc;
    }
    __syncthreads();
    // v (2x80), position update, output write
    if (tid < 12) {
      int r = tid & 1, a = tid >> 1;
      float acc = bd4S[r];
      for (int k4 = 0; k4 < 20; ++k4) {
        float4 xv = *(const float4*)&u3S[a][k4 * 4];
        float4 w = *(const float4*)&Wd4[(size_t)r * 80 + k4 * 4];
        DOT4(acc, w, xv);
      }
      float p = acc + lastS[a][r];
      lastS[a][r] = p;
      lastS[a][2 + r] = acc;
      out[(size_t)(n0 + a) * 48 + s * 4 + r] = p;
      out[(size_t)(n0 + a) * 48 + s * 4 + 2 + r] = acc;
    }
    __syncthreads();
    // xe = new_last @ Wemb^T + bemb
    for (int e = tid; e < 6 * 128; e += 512) {
      int a = e >> 7, j = e & 127;
      float4 w = *(const float4*)&WembS[j * 4];
      xeS[a][j] = bembS[j] + lastS[a][0] * w.x + lastS[a][1] * w.y + lastS[a][2] * w.z + lastS[a][3] * w.w;
    }
    __syncthreads();
    // z = xe @ Wih^T + h @ Whh^T + bz   (512 rows)
    for (int task = tid; task < 768; task += 512) {
      int r = (task & 127) * 4, a = task >> 7;
      float4 acc = make_float4(bzS[r], bzS[r + 1], bzS[r + 2], bzS[r + 3]);
      for (int k4 = 0; k4 < 32; ++k4) {
        float4 xv = *(const float4*)&xeS[a][k4 * 4];
        float4 w0 = *(const float4*)&Wih[(size_t)(r + 0) * 128 + k4 * 4];
        float4 w1 = *(const float4*)&Wih[(size_t)(r + 1) * 128 + k4 * 4];
        float4 w2 = *(const float4*)&Wih[(size_t)(r + 2) * 128 + k4 * 4];
        float4 w3 = *(const float4*)&Wih[(size_t)(r + 3) * 128 + k4 * 4];
        DOT4(acc.x, w0, xv);
        DOT4(acc.y, w1, xv);
        DOT4(acc.z, w2, xv);
        DOT4(acc.w, w3, xv);
      }
      for (int k4 = 0; k4 < 32; ++k4) {
        float4 hv = *(const float4*)&hS[a][k4 * 4];
        float4 w0 = *(const float4*)&Whh[(size_t)(r + 0) * 128 + k4 * 4];
        float4 w1 = *(const float4*)&Whh[(size_t)(r + 1) * 128 + k4 * 4];
        float4 w2 = *(const float4*)&Whh[(size_t)(r + 2) * 128 + k4 * 4];
        float4 w3 = *(const float4*)&Whh[(size_t)(r + 3) * 128 + k4 * 4];
        DOT4(acc.x, w0, hv);
        DOT4(acc.y, w1, hv);
        DOT4(acc.z, w2, hv);
        DOT4(acc.w, w3, hv);
      }
      *(float4*)&zS[a][r] = acc;
    }
    __syncthreads();
    // gates
    for (int e = tid; e < 6 * 128; e += 512) {
      int a = e >> 7, j = e & 127;
      float ci = sigm(zS[a][j + 128]) * cS[a][j] + sigm(zS[a][j]) * tanhf(zS[a][j + 256]);
      cS[a][j] = ci;
      hS[a][j] = sigm(zS[a][j + 384]) * tanhf(ci);
    }
    __syncthreads();
  }
}

extern "C" void kernel_launch(void* const* d_in, const int* in_sizes, int n_in,
                              void* d_out, int out_size, void* d_ws, size_t ws_size,
                              hipStream_t stream)
{
  const float* obsv = (const float*)d_in[0];
  const float* noise = (const float*)d_in[1];
  const float* Wemb = (const float*)d_in[2];
  const float* bemb = (const float*)d_in[3];
  const float* Wih = (const float*)d_in[4];
  const float* Whh = (const float*)d_in[5];
  const float* bih = (const float*)d_in[6];
  const float* bhh = (const float*)d_in[7];
  const float* Wf1 = (const float*)d_in[8];
  const float* bf1 = (const float*)d_in[9];
  const float* Wf2 = (const float*)d_in[10];
  const float* bf2 = (const float*)d_in[11];
  const float* Wf3 = (const float*)d_in[12];
  const float* bf3 = (const float*)d_in[13];
  const float* Wa = (const float*)d_in[14];
  const float* ba = (const float*)d_in[15];
  const float* Wd1 = (const float*)d_in[16];
  const float* bd1 = (const float*)d_in[17];
  const float* Wd2 = (const float*)d_in[18];
  const float* bd2 = (const float*)d_in[19];
  const float* Wd3 = (const float*)d_in[20];
  const float* bd3 = (const float*)d_in[21];
  const float* Wd4 = (const float*)d_in[22];
  const float* bd4 = (const float*)d_in[23];
  float* ws = (float*)d_ws;
  float* out = (float*)d_out;

  k_zx<<<384, 256, 0, stream>>>(obsv, Wemb, bemb, Wih, bih, bhh, ws);
  k_enc<<<192, 128, 0, stream>>>(Whh, ws);
  k_social<<<768, 128, 0, stream>>>(Wa, ba, Wf3, bf3, ws);
  k_attn<<<768, 64, 0, stream>>>(obsv, Wf1, bf1, Wf2, bf2, ws);
  k_dec<<<128, 512, 0, stream>>>(obsv, noise, Wemb, bemb, Wih, Whh, bih, bhh,
                                 Wd1, bd1, Wd2, bd2, Wd3, bd3, Wd4, bd4, ws, out);
}

// Round 4
// 348.030 us; speedup vs baseline: 7.8689x; 7.8689x over previous
//
#include <hip/hip_runtime.h>
#include <math.h>

// N=768, T=8, H=128, F=128, NZ=64, G=64, D=320, n_next=12
// ws float offsets (total ~2.64 MB)
#define H_OFF    0         // [768][128]
#define C_OFF    98304     // [768][128]
#define G_OFF    196608    // [768][64]
#define S0_OFF   245760    // [768]
#define WTD_OFF  246528    // [768][128]
#define TIH_OFF  344832    // WihT [128][512]
#define THH_OFF  410368    // WhhT [128][512]
#define TD1_OFF  475904    // Wd1T [320][320]
#define TD2_OFF  578304    // Wd2T [320][160]
#define TD3_OFF  629504    // Wd3T [160][80]
#define TWA_OFF  642304    // WaT  [128][128]
#define BZ_OFF   658688    // bih+bhh [512]

__device__ __forceinline__ float sigm(float x) { return 1.0f / (1.0f + __expf(-x)); }
__device__ __forceinline__ float lrelu(float u) { return u >= 0.f ? u : 0.2f * u; }

// ---------------- one-time weight transposes + bias fold ----------------
__global__ __launch_bounds__(256) void k_tr(
    const float* __restrict__ Wih, const float* __restrict__ Whh,
    const float* __restrict__ Wd1, const float* __restrict__ Wd2,
    const float* __restrict__ Wd3, const float* __restrict__ Wa,
    const float* __restrict__ bih, const float* __restrict__ bhh,
    float* __restrict__ ws)
{
  const int idx = blockIdx.x * 256 + threadIdx.x;
  if (idx < 65536) {  // [512][128] -> [128][512]
    int k = idx >> 9, r = idx & 511;
    ws[TIH_OFF + idx] = Wih[(size_t)r * 128 + k];
    ws[THH_OFF + idx] = Whh[(size_t)r * 128 + k];
  }
  if (idx < 102400) { int k = idx / 320, r = idx % 320; ws[TD1_OFF + idx] = Wd1[(size_t)r * 320 + k]; }
  if (idx < 51200)  { int k = idx / 160, r = idx % 160; ws[TD2_OFF + idx] = Wd2[(size_t)r * 320 + k]; }
  if (idx < 12800)  { int k = idx / 80,  r = idx % 80;  ws[TD3_OFF + idx] = Wd3[(size_t)r * 160 + k]; }
  if (idx < 16384)  { int k = idx >> 7,  r = idx & 127; ws[TWA_OFF + idx] = Wa[(size_t)r * 128 + k]; }
  if (idx < 512)    ws[BZ_OFF + idx] = bih[idx] + bhh[idx];
}

// ---------------- encoder LSTM: emb fused, 3 agents/block, 8 waves ----------------
__global__ __launch_bounds__(512) void k_enc(
    const float* __restrict__ obsv, const float* __restrict__ Wemb,
    const float* __restrict__ bemb, float* __restrict__ ws)
{
  __shared__ float hS[3][128], cS[3][128], zS[3][512], xeS[3][128];
  __shared__ float WembS[512], bembS[128];
  const int tid = threadIdx.x;
  const int wid = tid >> 6, lane = tid & 63;
  const int n0 = blockIdx.x * 3;
  const int row = wid * 64 + lane;

  WembS[tid] = Wemb[tid];
  if (tid < 128) bembS[tid] = bemb[tid];
  if (tid < 384) { int a = tid >> 7, j = tid & 127; hS[a][j] = 0.f; cS[a][j] = 0.f; }
  __syncthreads();

  const float bzv = ws[BZ_OFF + row];

  for (int step = 0; step < 8; ++step) {
    if (tid < 384) {
      int a = tid >> 7, j = tid & 127;
      float4 ob = *(const float4*)&obsv[((size_t)(n0 + a) * 8 + step) * 4];
      float4 w = *(const float4*)&WembS[j * 4];
      xeS[a][j] = bembS[j] + ob.x * w.x + ob.y * w.y + ob.z * w.z + ob.w * w.w;
    }
    __syncthreads();
    float a0 = bzv, a1 = bzv, a2 = bzv;
    const float* wih = &ws[TIH_OFF + row];
#pragma unroll 8
    for (int k = 0; k < 128; ++k) {
      float wv = wih[(size_t)k * 512];
      a0 += wv * xeS[0][k]; a1 += wv * xeS[1][k]; a2 += wv * xeS[2][k];
    }
    if (step > 0) {
      const float* whh = &ws[THH_OFF + row];
#pragma unroll 8
      for (int k = 0; k < 128; ++k) {
        float wv = whh[(size_t)k * 512];
        a0 += wv * hS[0][k]; a1 += wv * hS[1][k]; a2 += wv * hS[2][k];
      }
    }
    zS[0][row] = a0; zS[1][row] = a1; zS[2][row] = a2;
    __syncthreads();
    if (tid < 384) {
      int a = tid >> 7, j = tid & 127;
      float ci = sigm(zS[a][j + 128]) * cS[a][j] + sigm(zS[a][j]) * tanhf(zS[a][j + 256]);
      cS[a][j] = ci;
      hS[a][j] = sigm(zS[a][j + 384]) * tanhf(ci);
    }
    __syncthreads();
  }
  if (tid < 384) {
    int a = tid >> 7, j = tid & 127;
    ws[H_OFF + (size_t)(n0 + a) * 128 + j] = hS[a][j];
    ws[C_OFF + (size_t)(n0 + a) * 128 + j] = cS[a][j];
  }
}

// ---------------- social fold: Wh = h@Wa^T + ba ; g = Wf3^T Wh ; s0 = bf3 . Wh ----------------
__global__ __launch_bounds__(128) void k_social(
    const float* __restrict__ ba, const float* __restrict__ Wf3,
    const float* __restrict__ bf3, float* __restrict__ ws)
{
  __shared__ float hsh[128];
  __shared__ float Wh[128];
  const int n = blockIdx.x, t = threadIdx.x;
  hsh[t] = ws[H_OFF + (size_t)n * 128 + t];
  __syncthreads();
  float acc = ba[t];
#pragma unroll 8
  for (int k = 0; k < 128; ++k) acc += ws[TWA_OFF + (size_t)k * 128 + t] * hsh[k];
  Wh[t] = acc;
  __syncthreads();
  if (t < 64) {
    float g = 0.f;
#pragma unroll 8
    for (int f = 0; f < 128; ++f) g += Wf3[(size_t)f * 64 + t] * Wh[f];
    ws[G_OFF + (size_t)n * 64 + t] = g;
  } else {
    int l = t - 64;
    float p = bf3[l] * Wh[l] + bf3[l + 64] * Wh[l + 64];
    for (int off = 32; off > 0; off >>= 1) p += __shfl_xor(p, off);
    if (l == 0) ws[S0_OFF + n] = p;
  }
}

// ---------------- pair features + MLP(3->32->64) + sigma + softmax + S ----------------
__global__ __launch_bounds__(64) void k_attn(
    const float* __restrict__ obsv, const float* __restrict__ Wf1,
    const float* __restrict__ bf1, const float* __restrict__ Wf2,
    const float* __restrict__ bf2, float* __restrict__ ws)
{
  __shared__ float w1[96];
  __shared__ float b1[32];
  __shared__ float w2[2048];
  __shared__ float b2[64];
  __shared__ float attn_s[64];
  __shared__ float xi[4];

  const int i = blockIdx.x;
  const int b = i >> 6;
  const int lane = threadIdx.x;
  const int jn = (b << 6) + lane;

  for (int e = lane; e < 96; e += 64) w1[e] = Wf1[e];
  if (lane < 32) b1[lane] = bf1[lane];
  for (int e = lane; e < 2048; e += 64) w2[e] = Wf2[e];
  b2[lane] = bf2[lane];
  if (lane < 4) xi[lane] = obsv[((size_t)i * 8 + 7) * 4 + lane];
  __syncthreads();

  float4 xj = *(const float4*)&obsv[((size_t)jn * 8 + 7) * 4];
  float dpx = xi[0] - xj.x, dpy = xi[1] - xj.y;
  float vix = xi[2], viy = xi[3];
  float dvx = vix - xj.z, dvy = viy - xj.w;
  float l2 = sqrtf(dpx * dpx + dpy * dpy);
  float vnorm = sqrtf(vix * vix + viy * viy);
  float cosv = (dpx * vix + dpy * viy) / (l2 * vnorm + 1e-6f);
  float dv2 = dvx * dvx + dvy * dvy;
  float ttca = -(dpx * dvx + dpy * dvy) / (dv2 + 1e-6f);
  float cax = dpx + ttca * dvx, cay = dpy + ttca * dvy;
  float dca = sqrtf(cax * cax + cay * cay);

  float e1[32];
#pragma unroll
  for (int r = 0; r < 32; ++r)
    e1[r] = fmaxf(w1[r * 3 + 0] * l2 + w1[r * 3 + 1] * cosv + w1[r * 3 + 2] * dca + b1[r], 0.f);

  const float* gp = &ws[G_OFF + (size_t)jn * 64];
  float sig = ws[S0_OFF + jn];
  for (int r = 0; r < 64; ++r) {
    float a2 = b2[r];
#pragma unroll
    for (int k4 = 0; k4 < 8; ++k4) {
      float4 w = *(const float4*)&w2[r * 32 + k4 * 4];
      a2 += w.x * e1[k4 * 4 + 0] + w.y * e1[k4 * 4 + 1] + w.z * e1[k4 * 4 + 2] + w.w * e1[k4 * 4 + 3];
    }
    a2 = fmaxf(a2, 0.f);
    sig += a2 * gp[r];
  }
  if (lane == (i & 63)) sig = -1000.f;

  float m = sig;
  for (int off = 32; off > 0; off >>= 1) m = fmaxf(m, __shfl_xor(m, off));
  float ex = __expf(sig - m);
  float ssum = ex;
  for (int off = 32; off > 0; off >>= 1) ssum += __shfl_xor(ssum, off);
  attn_s[lane] = ex / ssum;
  __syncthreads();

  const float* hbase = &ws[H_OFF + (size_t)(b << 6) * 128];
  float s0a = 0.f, s1a = 0.f;
  for (int j = 0; j < 64; ++j) {
    float aj = attn_s[j];
    s0a += aj * hbase[(size_t)j * 128 + lane];
    s1a += aj * hbase[(size_t)j * 128 + 64 + lane];
  }
  ws[WTD_OFF + (size_t)i * 128 + lane] = s0a;
  ws[WTD_OFF + (size_t)i * 128 + 64 + lane] = s1a;
}

// ---------------- decoder: 12 fused steps, 3 agents/block, grid 256 ----------------
__global__ __launch_bounds__(512) void k_dec(
    const float* __restrict__ obsv, const float* __restrict__ noise,
    const float* __restrict__ Wemb, const float* __restrict__ bemb,
    const float* __restrict__ bd1, const float* __restrict__ bd2,
    const float* __restrict__ bd3, const float* __restrict__ bd4,
    const float* __restrict__ Wd4,
    float* __restrict__ ws, float* __restrict__ out)
{
  __shared__ float inpS[3][320], u1S[3][320], u2S[3][160], u3S[3][80];
  __shared__ float cS[3][128], xeS[3][128], zS[3][512];
  __shared__ float lastS[3][4];
  __shared__ float bd1S[320], bd2S[160], bd3S[80], bd4S[2], Wd4S[160];
  __shared__ float WembS[512], bembS[128], bzS[512];

  const int tid = threadIdx.x;
  const int wid = tid >> 6, lane = tid & 63;
  const int n0 = blockIdx.x * 3;

  if (tid < 384) {
    int a = tid >> 7, j = tid & 127;
    inpS[a][j] = ws[H_OFF + (size_t)(n0 + a) * 128 + j];
    inpS[a][128 + j] = ws[WTD_OFF + (size_t)(n0 + a) * 128 + j];
    if (j < 64) inpS[a][256 + j] = noise[(size_t)(n0 + a) * 64 + j];
    cS[a][j] = ws[C_OFF + (size_t)(n0 + a) * 128 + j];
  }
  WembS[tid] = Wemb[tid];
  bzS[tid] = ws[BZ_OFF + tid];
  if (tid < 320) bd1S[tid] = bd1[tid];
  if (tid < 160) { bd2S[tid] = bd2[tid]; Wd4S[tid] = Wd4[tid]; }
  if (tid < 128) bembS[tid] = bemb[tid];
  if (tid < 80) bd3S[tid] = bd3[tid];
  if (tid < 2) bd4S[tid] = bd4[tid];
  if (tid < 12) {
    int a = tid >> 2, r = tid & 3;
    lastS[a][r] = obsv[((size_t)(n0 + a) * 8 + 7) * 4 + r];
  }
  __syncthreads();

  for (int s = 0; s < 12; ++s) {
    // u1 = lrelu(inp @ Wd1^T + bd1): 320 rows, waves 0..4 row-stationary
    if (wid < 5) {
      const int r = wid * 64 + lane;
      float a0 = bd1S[r], a1 = a0, a2 = a0;
      const float* wp = &ws[TD1_OFF + r];
#pragma unroll 8
      for (int k = 0; k < 320; ++k) {
        float wv = wp[(size_t)k * 320];
        a0 += wv * inpS[0][k]; a1 += wv * inpS[1][k]; a2 += wv * inpS[2][k];
      }
      u1S[0][r] = lrelu(a0); u1S[1][r] = lrelu(a1); u1S[2][r] = lrelu(a2);
    }
    __syncthreads();
    // u2: 160 rows, k=320 split in 2 half-k groups per wave
    if (wid < 5) {
      const int r = wid * 32 + (lane & 31);
      const int kb = (lane >> 5) * 160;
      float a0 = 0.f, a1 = 0.f, a2 = 0.f;
      const float* wp = &ws[TD2_OFF + r];
#pragma unroll 8
      for (int i2 = 0; i2 < 160; ++i2) {
        int k = kb + i2;
        float wv = wp[(size_t)k * 160];
        a0 += wv * u1S[0][k]; a1 += wv * u1S[1][k]; a2 += wv * u1S[2][k];
      }
      a0 += __shfl_xor(a0, 32); a1 += __shfl_xor(a1, 32); a2 += __shfl_xor(a2, 32);
      if (lane < 32) {
        float bb = bd2S[r];
        u2S[0][r] = lrelu(a0 + bb); u2S[1][r] = lrelu(a1 + bb); u2S[2][r] = lrelu(a2 + bb);
      }
    }
    __syncthreads();
    // u3: 80 rows, k=160 split in 4 quarter-k groups
    if (wid < 5) {
      const int r = wid * 16 + (lane & 15);
      const int kb = (lane >> 4) * 40;
      float a0 = 0.f, a1 = 0.f, a2 = 0.f;
      const float* wp = &ws[TD3_OFF + r];
#pragma unroll 8
      for (int i2 = 0; i2 < 40; ++i2) {
        int k = kb + i2;
        float wv = wp[(size_t)k * 80];
        a0 += wv * u2S[0][k]; a1 += wv * u2S[1][k]; a2 += wv * u2S[2][k];
      }
      a0 += __shfl_xor(a0, 16); a1 += __shfl_xor(a1, 16); a2 += __shfl_xor(a2, 16);
      a0 += __shfl_xor(a0, 32); a1 += __shfl_xor(a1, 32); a2 += __shfl_xor(a2, 32);
      if (lane < 16) {
        float bb = bd3S[r];
        u3S[0][r] = a0 + bb; u3S[1][r] = a1 + bb; u3S[2][r] = a2 + bb;
      }
    }
    __syncthreads();
    // v = u3 @ Wd4^T + bd4 (2 rows); position update; output
    if (wid < 3) {
      const int a = wid;
      float q0 = Wd4S[lane] * u3S[a][lane];
      float q1 = Wd4S[80 + lane] * u3S[a][lane];
      if (lane < 16) {
        q0 += Wd4S[64 + lane] * u3S[a][64 + lane];
        q1 += Wd4S[144 + lane] * u3S[a][64 + lane];
      }
      for (int off = 32; off > 0; off >>= 1) { q0 += __shfl_xor(q0, off); q1 += __shfl_xor(q1, off); }
      if (lane == 0) {
        float v0 = q0 + bd4S[0], v1 = q1 + bd4S[1];
        float p0 = v0 + lastS[a][0], p1 = v1 + lastS[a][1];
        lastS[a][0] = p0; lastS[a][1] = p1; lastS[a][2] = v0; lastS[a][3] = v1;
        float* op = &out[(size_t)(n0 + a) * 48 + s * 4];
        op[0] = p0; op[1] = p1; op[2] = v0; op[3] = v1;
      }
    }
    __syncthreads();
    // xe = new_last @ Wemb^T + bemb
    if (tid < 384) {
      int a = tid >> 7, j = tid & 127;
      float4 w = *(const float4*)&WembS[j * 4];
      xeS[a][j] = bembS[j] + lastS[a][0] * w.x + lastS[a][1] * w.y + lastS[a][2] * w.z + lastS[a][3] * w.w;
    }
    __syncthreads();
    // z = xe @ Wih^T + h @ Whh^T + bz: 512 rows, all 8 waves
    {
      const int row = wid * 64 + lane;
      float a0 = bzS[row], a1 = a0, a2 = a0;
      const float* wih = &ws[TIH_OFF + row];
#pragma unroll 8
      for (int k = 0; k < 128; ++k) {
        float wv = wih[(size_t)k * 512];
        a0 += wv * xeS[0][k]; a1 += wv * xeS[1][k]; a2 += wv * xeS[2][k];
      }
      const float* whh = &ws[THH_OFF + row];
#pragma unroll 8
      for (int k = 0; k < 128; ++k) {
        float wv = whh[(size_t)k * 512];
        a0 += wv * inpS[0][k]; a1 += wv * inpS[1][k]; a2 += wv * inpS[2][k];
      }
      zS[0][row] = a0; zS[1][row] = a1; zS[2][row] = a2;
    }
    __syncthreads();
    // gates: update c and h (h lives in inpS[:, 0:128])
    if (tid < 384) {
      int a = tid >> 7, j = tid & 127;
      float ci = sigm(zS[a][j + 128]) * cS[a][j] + sigm(zS[a][j]) * tanhf(zS[a][j + 256]);
      cS[a][j] = ci;
      inpS[a][j] = sigm(zS[a][j + 384]) * tanhf(ci);
    }
    __syncthreads();
  }
}

extern "C" void kernel_launch(void* const* d_in, const int* in_sizes, int n_in,
                              void* d_out, int out_size, void* d_ws, size_t ws_size,
                              hipStream_t stream)
{
  const float* obsv = (const float*)d_in[0];
  const float* noise = (const float*)d_in[1];
  const float* Wemb = (const float*)d_in[2];
  const float* bemb = (const float*)d_in[3];
  const float* Wih = (const float*)d_in[4];
  const float* Whh = (const float*)d_in[5];
  const float* bih = (const float*)d_in[6];
  const float* bhh = (const float*)d_in[7];
  const float* Wf1 = (const float*)d_in[8];
  const float* bf1 = (const float*)d_in[9];
  const float* Wf2 = (const float*)d_in[10];
  const float* bf2 = (const float*)d_in[11];
  const float* Wf3 = (const float*)d_in[12];
  const float* bf3 = (const float*)d_in[13];
  const float* Wa = (const float*)d_in[14];
  const float* ba = (const float*)d_in[15];
  const float* Wd1 = (const float*)d_in[16];
  const float* bd1 = (const float*)d_in[17];
  const float* Wd2 = (const float*)d_in[18];
  const float* bd2 = (const float*)d_in[19];
  const float* Wd3 = (const float*)d_in[20];
  const float* bd3 = (const float*)d_in[21];
  const float* Wd4 = (const float*)d_in[22];
  const float* bd4 = (const float*)d_in[23];
  float* ws = (float*)d_ws;
  float* out = (float*)d_out;

  k_tr<<<400, 256, 0, stream>>>(Wih, Whh, Wd1, Wd2, Wd3, Wa, bih, bhh, ws);
  k_enc<<<256, 512, 0, stream>>>(obsv, Wemb, bemb, ws);
  k_social<<<768, 128, 0, stream>>>(ba, Wf3, bf3, ws);
  k_attn<<<768, 64, 0, stream>>>(obsv, Wf1, bf1, Wf2, bf2, ws);
  k_dec<<<256, 512, 0, stream>>>(obsv, noise, Wemb, bemb, bd1, bd2, bd3, bd4, Wd4, ws, out);
}